// Round 2
// baseline (893.055 us; speedup 1.0000x reference)
//
#include <hip/hip_runtime.h>

#define NB 32
#define NP 24564
#define NOBJ 50
#define NC1 20          // NUM_CLASSES - 1
#define WTHRESH 0.5f

typedef unsigned long long u64;
typedef unsigned int u32;

// monotone float->uint mapping (works for all floats; our ranked values are >= 0)
__device__ __forceinline__ u32 f2s(float f){
  u32 u = __float_as_uint(f);
  return (u & 0x80000000u) ? ~u : (u | 0x80000000u);
}

// ---------------- init ----------------
__global__ __launch_bounds__(256) void k_init(int* ovr, u64* bpKey, int* numPos, double* acc){
  int i = blockIdx.x*256 + threadIdx.x;
  if (i < NB*NP)   ovr[i] = -1;
  if (i < NB*NOBJ) bpKey[i] = 0ull;
  if (i < NB)      numPos[i] = 0;
  if (i < 4)       acc[i] = 0.0;
}

// ---------------- match: IOU, best-truth per prior, best-prior per truth ----------------
__global__ __launch_bounds__(256) void k_match(const float* __restrict__ priors,
    const float* __restrict__ targets, float* __restrict__ ovArr,
    int* __restrict__ btIdx, u64* __restrict__ bpKey){
  const int b = blockIdx.y;
  const int j = blockIdx.x*256 + threadIdx.x;
  __shared__ float tr[NOBJ*5];
  if (threadIdx.x < NOBJ*5) tr[threadIdx.x] = targets[b*NOBJ*5 + threadIdx.x];
  __syncthreads();
  const bool valid = (j < NP);
  float px1=0.f,py1=0.f,px2=0.f,py2=0.f, areaB=0.f;
  if (valid){
    float4 pr = reinterpret_cast<const float4*>(priors)[j];
    px1 = pr.x - pr.z*0.5f; py1 = pr.y - pr.w*0.5f;
    px2 = pr.x + pr.z*0.5f; py2 = pr.y + pr.w*0.5f;
    areaB = (px2-px1)*(py2-py1);
  }
  float bestOv = -1.0f; int bestT = 0;
  for (int t=0; t<NOBJ; t++){
    float iou = 0.0f;
    if (valid){
      float tx1=tr[t*5+0], ty1=tr[t*5+1], tx2=tr[t*5+2], ty2=tr[t*5+3];
      float w = fmaxf(fminf(tx2,px2)-fmaxf(tx1,px1), 0.f);
      float h = fmaxf(fminf(ty2,py2)-fmaxf(ty1,py1), 0.f);
      float inter = w*h;
      float areaA = (tx2-tx1)*(ty2-ty1);
      iou = inter / (areaA + areaB - inter);
      if (iou > bestOv){ bestOv = iou; bestT = t; }   // strict > == first occurrence (axis=0 argmax)
    }
    // per-truth argmax over priors; tie -> smallest j (JAX first occurrence)
    u64 key = valid ? (((u64)f2s(iou) << 32) | (u64)(u32)(~(u32)j)) : 0ull;
    #pragma unroll
    for (int off=32; off>0; off>>=1){
      u64 o = (((u64)__shfl_down((u32)(key>>32), off)) << 32) | (u64)__shfl_down((u32)key, off);
      if (o > key) key = o;
    }
    if ((threadIdx.x & 63) == 0) atomicMax(&bpKey[b*NOBJ + t], key);
  }
  if (valid){
    ovArr[(size_t)b*NP + j] = bestOv;
    btIdx[(size_t)b*NP + j] = bestT;
  }
}

// ---------------- scatter: force each truth's best prior ----------------
__global__ __launch_bounds__(256) void k_scatter(const u64* __restrict__ bpKey,
    float* __restrict__ ovArr, int* __restrict__ ovr){
  int i = blockIdx.x*256 + threadIdx.x;
  if (i >= NB*NOBJ) return;
  int b = i / NOBJ;
  int t = i % NOBJ;
  u64 key = bpKey[i];
  int j = (int)(~(u32)key);
  ovArr[(size_t)b*NP + j] = 2.0f;                 // .at[best_prior_idx].set(2.0)
  atomicMax(&ovr[(size_t)b*NP + j], t);           // .at[best_prior_idx].max(arange)
}

// ---------------- per-prior losses + pos mask + pos-side sums ----------------
// ceBinOut aliases ovArr, ceMulOut aliases btIdx (read-before-write per thread) -> no __restrict__.
__global__ __launch_bounds__(256) void k_loss(
    const float* loc, const float* conf, const float* binc,
    const float* priors, const float* targets,
    const float* ovArr, const int* btIdx, const int* ovr,
    float* ceBinOut, float* ceMulOut, float* posOut, int* numPos, double* acc){
  const int b = blockIdx.y;
  const int j = blockIdx.x*256 + threadIdx.x;
  __shared__ float tr[NOBJ*5];
  if (threadIdx.x < NOBJ*5) tr[threadIdx.x] = targets[b*NOBJ*5 + threadIdx.x];
  __syncthreads();
  float sl1=0.f, ceB=0.f, ceM=0.f; int isPos=0;
  if (j < NP){
    const size_t idx = (size_t)b*NP + j;
    float ov = ovArr[idx];
    int o = ovr[idx];
    int ti = (o >= 0) ? o : btIdx[idx];
    float tx1=tr[ti*5+0], ty1=tr[ti*5+1], tx2=tr[ti*5+2], ty2=tr[ti*5+3], lab=tr[ti*5+4];
    int conf_t = (ov < WTHRESH) ? 0 : ((int)lab + 1);
    isPos = (conf_t > 0) ? 1 : 0;
    // encode
    float4 pr = reinterpret_cast<const float4*>(priors)[j];
    float gcx = ((tx1+tx2)*0.5f - pr.x) / (0.1f*pr.z);
    float gcy = ((ty1+ty2)*0.5f - pr.y) / (0.1f*pr.w);
    float gw  = logf((tx2-tx1)/pr.z) / 0.2f;
    float gh  = logf((ty2-ty1)/pr.w) / 0.2f;
    float4 ld = reinterpret_cast<const float4*>(loc)[idx];
    float d0=fabsf(ld.x-gcx), d1=fabsf(ld.y-gcy), d2=fabsf(ld.z-gw), d3=fabsf(ld.w-gh);
    sl1  = (d0<1.f ? 0.5f*d0*d0 : d0-0.5f);
    sl1 += (d1<1.f ? 0.5f*d1*d1 : d1-0.5f);
    sl1 += (d2<1.f ? 0.5f*d2*d2 : d2-0.5f);
    sl1 += (d3<1.f ? 0.5f*d3*d3 : d3-0.5f);
    // binary CE
    float2 bc = reinterpret_cast<const float2*>(binc)[idx];
    float mB = fmaxf(bc.x, bc.y);
    float lseB = logf(expf(bc.x-mB)+expf(bc.y-mB)) + mB;
    ceB = lseB - (isPos ? bc.y : bc.x);
    // multiclass CE over P_logit = [bin0+lse(conf), conf+bin1]
    float c[NC1];
    const float4* cp = reinterpret_cast<const float4*>(conf + idx*NC1);
    #pragma unroll
    for (int q=0;q<5;q++){ float4 v=cp[q]; c[q*4]=v.x; c[q*4+1]=v.y; c[q*4+2]=v.z; c[q*4+3]=v.w; }
    float mc = c[0];
    #pragma unroll
    for (int q=1;q<NC1;q++) mc = fmaxf(mc, c[q]);
    float se = 0.f;
    #pragma unroll
    for (int q=0;q<NC1;q++) se += expf(c[q]-mc);
    float lseC = logf(se) + mc;
    float P0 = bc.x + lseC;
    float m2 = fmaxf(P0, mc + bc.y);
    float s2 = expf(P0 - m2);
    #pragma unroll
    for (int q=0;q<NC1;q++) s2 += expf(c[q] + bc.y - m2);
    float lseM = logf(s2) + m2;
    float g = (conf_t==0) ? P0 : (c[conf_t-1] + bc.y);
    ceM = lseM - g;
    ceBinOut[idx] = isPos ? 0.f : ceB;
    ceMulOut[idx] = isPos ? 0.f : ceM;
    posOut[idx] = isPos ? 1.f : 0.f;
  }
  float a0 = isPos ? sl1 : 0.f;
  float a1 = isPos ? ceM : 0.f;
  float a2 = isPos ? ceB : 0.f;
  int cnt = isPos;
  #pragma unroll
  for (int off=32; off>0; off>>=1){
    a0 += __shfl_down(a0, off);
    a1 += __shfl_down(a1, off);
    a2 += __shfl_down(a2, off);
    cnt += __shfl_down(cnt, off);
  }
  if ((threadIdx.x & 63) == 0){
    if (cnt)        atomicAdd(&numPos[b], cnt);
    if (a0 != 0.f)  atomicAdd(&acc[0], (double)a0);
    if (a1 != 0.f)  atomicAdd(&acc[1], (double)a1);
    if (a2 != 0.f)  atomicAdd(&acc[2], (double)a2);
  }
}

// ---------------- exact top-k selection per row (stable-argsort semantics) ----------------
__global__ __launch_bounds__(256) void k_rank(const float* __restrict__ ceBin,
    const float* __restrict__ ceMul, const int* __restrict__ numPos,
    float* __restrict__ negBinOut, float* __restrict__ negMulOut, double* acc){
  const int b = blockIdx.x;
  const int which = blockIdx.y;        // 0 = binary loss, 1 = multiclass loss
  const float* arr = (which==0 ? ceBin : ceMul) + (size_t)b*NP;
  float* out = (which==0 ? negBinOut : negMulOut) + (size_t)b*NP;
  const int tid = threadIdx.x;
  int np = numPos[b];
  int k = min(3*np, NP-1);
  if (k <= 0){
    for (int i=tid; i<NP; i+=256) out[i] = 0.f;
    return;
  }
  __shared__ u32 hist[256];
  __shared__ u32 s_pref;
  __shared__ int s_rem;
  if (tid==0){ s_pref = 0u; s_rem = k; }
  __syncthreads();
  for (int r=0; r<4; r++){
    u32 pref = s_pref;
    hist[tid] = 0u;
    __syncthreads();
    int sh = 24 - 8*r;
    for (int i=tid; i<NP; i+=256){
      u32 s = f2s(arr[i]);
      if (r==0 || (s >> (sh+8)) == (pref >> (sh+8)))
        atomicAdd(&hist[(s >> sh) & 255u], 1u);
    }
    __syncthreads();
    if (tid==0){
      u32 rem = (u32)s_rem;
      u32 cum = 0; int chosen = 0;
      for (int bin=255; bin>=0; bin--){
        u32 h = hist[bin];
        if (cum + h >= rem){ chosen = bin; s_rem = (int)(rem - cum); break; }
        cum += h;
      }
      s_pref = pref | ((u32)chosen << sh);
    }
    __syncthreads();
  }
  const u32 kth = s_pref;     // exact k-th largest key
  const int need = s_rem;     // how many of the ties (by smallest index) are selected
  __shared__ int eqCnt;
  __shared__ int eqIdx[2048];
  if (tid==0) eqCnt = 0;
  __syncthreads();
  float sum = 0.f;
  for (int i=tid; i<NP; i+=256){
    u32 s = f2s(arr[i]);
    float o = 0.f;
    if (s > kth){ o = 1.f; sum += arr[i]; }
    else if (s == kth){ int p = atomicAdd(&eqCnt, 1); if (p < 2048) eqIdx[p] = i; }
    out[i] = o;
  }
  __syncthreads();
  int ec = min(eqCnt, 2048);
  for (int e=tid; e<ec; e+=256){
    int idx = eqIdx[e]; int rank = 0;
    for (int f=0; f<ec; f++) rank += (eqIdx[f] < idx) ? 1 : 0;
    if (rank < need){ out[idx] = 1.f; sum += arr[idx]; }
  }
  if (which==0){
    #pragma unroll
    for (int off=32; off>0; off>>=1) sum += __shfl_down(sum, off);
    if ((tid & 63) == 0 && sum != 0.f) atomicAdd(&acc[3], (double)sum);
  }
}

// ---------------- finalize scalars ----------------
__global__ void k_final(const int* numPos, const double* acc, float* out){
  if (threadIdx.x==0 && blockIdx.x==0){
    int s = 0;
    for (int b=0; b<NB; b++) s += numPos[b];
    float N = fmaxf((float)s, 1.0f);
    out[0] = (float)(acc[0] / (double)N);                 // loss_l / N
    out[1] = (float)(acc[1] / (double)N);                 // loss_cls / N
    out[2] = (float)((acc[2] + 3.0*acc[3]) / (double)N);  // loss_b / N  (w_bin[0]=3 on negatives)
  }
}

extern "C" void kernel_launch(void* const* d_in, const int* in_sizes, int n_in,
                              void* d_out, int out_size, void* d_ws, size_t ws_size,
                              hipStream_t stream) {
  const float* loc     = (const float*)d_in[0];
  const float* conf    = (const float*)d_in[1];
  const float* binc    = (const float*)d_in[2];
  const float* priors  = (const float*)d_in[3];
  const float* targets = (const float*)d_in[4];
  float* out = (float*)d_out;

  char* ws = (char*)d_ws;
  float* ovArr  = (float*)ws;                                   // NB*NP f32 -> reused as ceBin
  int*   btIdx  = (int*)(ws + (size_t)NB*NP*4);                 // NB*NP i32 -> reused as ceMul
  int*   ovr    = (int*)(ws + (size_t)NB*NP*8);                 // NB*NP i32
  u64*   bpKey  = (u64*)(ws + (size_t)NB*NP*12);                // NB*NOBJ u64
  int*   numPos = (int*)(ws + (size_t)NB*NP*12 + NB*NOBJ*8);    // NB i32
  double* acc   = (double*)(ws + (size_t)NB*NP*12 + NB*NOBJ*8 + NB*4); // 4 f64

  float* posOut    = out + 3;
  float* negBinOut = out + 3 + (size_t)NB*NP;
  float* negMulOut = out + 3 + (size_t)2*NB*NP;

  const int pbBlocks = (NP + 255)/256;      // 96
  k_init<<<(NB*NP + 255)/256, 256, 0, stream>>>(ovr, bpKey, numPos, acc);
  k_match<<<dim3(pbBlocks, NB), 256, 0, stream>>>(priors, targets, ovArr, btIdx, bpKey);
  k_scatter<<<(NB*NOBJ + 255)/256, 256, 0, stream>>>(bpKey, ovArr, ovr);
  k_loss<<<dim3(pbBlocks, NB), 256, 0, stream>>>(loc, conf, binc, priors, targets,
      ovArr, btIdx, ovr, ovArr /*ceBin*/, (float*)btIdx /*ceMul*/, posOut, numPos, acc);
  k_rank<<<dim3(NB, 2), 256, 0, stream>>>(ovArr, (const float*)btIdx, numPos,
      negBinOut, negMulOut, acc);
  k_final<<<1, 64, 0, stream>>>(numPos, acc, out);
}

// Round 3
// 766.994 us; speedup vs baseline: 1.1644x; 1.1644x over previous
//
#include <hip/hip_runtime.h>

#define NB 32
#define NP 24564
#define NOBJ 50
#define NC1 20          // NUM_CLASSES - 1
#define WTHRESH 0.5f

typedef unsigned long long u64;
typedef unsigned int u32;

// monotone float->uint mapping (works for all floats; our ranked values are >= 0)
__device__ __forceinline__ u32 f2s(float f){
  u32 u = __float_as_uint(f);
  return (u & 0x80000000u) ? ~u : (u | 0x80000000u);
}

// ---------------- init ----------------
__global__ __launch_bounds__(256) void k_init(int* ovr, u64* bpKey, int* numPos, double* acc){
  int i = blockIdx.x*256 + threadIdx.x;
  if (i < NB*NP)   ovr[i] = -1;
  if (i < NB*NOBJ) bpKey[i] = 0ull;
  if (i < NB)      numPos[i] = 0;
  if (i < 4)       acc[i] = 0.0;
}

// ---------------- match: IOU, best-truth per prior, best-prior per truth ----------------
__global__ __launch_bounds__(256) void k_match(const float* __restrict__ priors,
    const float* __restrict__ targets, float* __restrict__ ovArr,
    int* __restrict__ btIdx, u64* __restrict__ bpKey){
  const int b = blockIdx.y;
  const int j = blockIdx.x*256 + threadIdx.x;
  __shared__ float tr[NOBJ*5];
  if (threadIdx.x < NOBJ*5) tr[threadIdx.x] = targets[b*NOBJ*5 + threadIdx.x];
  __syncthreads();
  const bool valid = (j < NP);
  const int waveBase = blockIdx.x*256 + (threadIdx.x & ~63);
  float px1=0.f,py1=0.f,px2=0.f,py2=0.f, areaB=0.f;
  if (valid){
    float4 pr = reinterpret_cast<const float4*>(priors)[j];
    px1 = pr.x - pr.z*0.5f; py1 = pr.y - pr.w*0.5f;
    px2 = pr.x + pr.z*0.5f; py2 = pr.y + pr.w*0.5f;
    areaB = (px2-px1)*(py2-py1);
  }
  float bestOv = -1.0f; int bestT = 0;
  for (int t=0; t<NOBJ; t++){
    float iou = 0.0f;
    if (valid){
      float tx1=tr[t*5+0], ty1=tr[t*5+1], tx2=tr[t*5+2], ty2=tr[t*5+3];
      float w = fmaxf(fminf(tx2,px2)-fmaxf(tx1,px1), 0.f);
      float h = fmaxf(fminf(ty2,py2)-fmaxf(ty1,py1), 0.f);
      float inter = w*h;
      float areaA = (tx2-tx1)*(ty2-ty1);
      iou = inter / (areaA + areaB - inter);
      if (iou > bestOv){ bestOv = iou; bestT = t; }   // strict > == first occurrence (axis=0 argmax)
    }
    // per-truth argmax over priors; tie -> smallest j (JAX first occurrence).
    // u32 wave-max + ballot to find lowest winning lane (half the shuffle cost of a u64 reduce).
    u32 key = valid ? f2s(iou) : 0u;
    u32 m = key;
    #pragma unroll
    for (int off=32; off>0; off>>=1){
      u32 o = __shfl_down(m, off);
      m = (o > m) ? o : m;
    }
    u32 kmax = __shfl(m, 0);
    u64 ball = __ballot(key == kmax);
    if ((threadIdx.x & 63) == 0 && kmax != 0u){
      int lane = __ffsll((unsigned long long)ball) - 1;
      u32 jwin = (u32)(waveBase + lane);
      u64 k64 = (((u64)kmax) << 32) | (u64)(~jwin);
      atomicMax(&bpKey[b*NOBJ + t], k64);
    }
  }
  if (valid){
    ovArr[(size_t)b*NP + j] = bestOv;
    btIdx[(size_t)b*NP + j] = bestT;
  }
}

// ---------------- scatter: force each truth's best prior ----------------
__global__ __launch_bounds__(256) void k_scatter(const u64* __restrict__ bpKey,
    float* __restrict__ ovArr, int* __restrict__ ovr){
  int i = blockIdx.x*256 + threadIdx.x;
  if (i >= NB*NOBJ) return;
  int b = i / NOBJ;
  int t = i % NOBJ;
  u64 key = bpKey[i];
  int j = (int)(~(u32)key);
  ovArr[(size_t)b*NP + j] = 2.0f;                 // .at[best_prior_idx].set(2.0)
  atomicMax(&ovr[(size_t)b*NP + j], t);           // .at[best_prior_idx].max(arange)
}

// ---------------- per-prior losses + pos mask + pos-side sums ----------------
// ceBinOut aliases ovArr, ceMulOut aliases btIdx (read-before-write per thread) -> no __restrict__.
// NOTE: no runtime indexing of c[] anywhere — keeps the array in VGPRs (rule #20).
__global__ __launch_bounds__(256) void k_loss(
    const float* loc, const float* conf, const float* binc,
    const float* priors, const float* targets,
    const float* ovArr, const int* btIdx, const int* ovr,
    float* ceBinOut, float* ceMulOut, float* posOut, int* numPos, double* acc){
  const int b = blockIdx.y;
  const int j = blockIdx.x*256 + threadIdx.x;
  __shared__ float tr[NOBJ*5];
  if (threadIdx.x < NOBJ*5) tr[threadIdx.x] = targets[b*NOBJ*5 + threadIdx.x];
  __syncthreads();
  float sl1=0.f, ceB=0.f, ceM=0.f; int isPos=0;
  if (j < NP){
    const size_t idx = (size_t)b*NP + j;
    float ov = ovArr[idx];
    int o = ovr[idx];
    int ti = (o >= 0) ? o : btIdx[idx];
    float tx1=tr[ti*5+0], ty1=tr[ti*5+1], tx2=tr[ti*5+2], ty2=tr[ti*5+3], lab=tr[ti*5+4];
    int conf_t = (ov < WTHRESH) ? 0 : ((int)lab + 1);
    isPos = (conf_t > 0) ? 1 : 0;
    // encode
    float4 pr = reinterpret_cast<const float4*>(priors)[j];
    float gcx = ((tx1+tx2)*0.5f - pr.x) / (0.1f*pr.z);
    float gcy = ((ty1+ty2)*0.5f - pr.y) / (0.1f*pr.w);
    float gw  = logf((tx2-tx1)/pr.z) / 0.2f;
    float gh  = logf((ty2-ty1)/pr.w) / 0.2f;
    float4 ld = reinterpret_cast<const float4*>(loc)[idx];
    float d0=fabsf(ld.x-gcx), d1=fabsf(ld.y-gcy), d2=fabsf(ld.z-gw), d3=fabsf(ld.w-gh);
    sl1  = (d0<1.f ? 0.5f*d0*d0 : d0-0.5f);
    sl1 += (d1<1.f ? 0.5f*d1*d1 : d1-0.5f);
    sl1 += (d2<1.f ? 0.5f*d2*d2 : d2-0.5f);
    sl1 += (d3<1.f ? 0.5f*d3*d3 : d3-0.5f);
    // binary CE
    float2 bc = reinterpret_cast<const float2*>(binc)[idx];
    float mB = fmaxf(bc.x, bc.y);
    float lseB = logf(expf(bc.x-mB)+expf(bc.y-mB)) + mB;
    ceB = lseB - (isPos ? bc.y : bc.x);
    // multiclass CE over P_logit = [bin0+lse(conf), conf+bin1]
    float c[NC1];
    const float4* cp = reinterpret_cast<const float4*>(conf + idx*NC1);
    #pragma unroll
    for (int q=0;q<5;q++){ float4 v=cp[q]; c[q*4]=v.x; c[q*4+1]=v.y; c[q*4+2]=v.z; c[q*4+3]=v.w; }
    float mc = c[0];
    #pragma unroll
    for (int q=1;q<NC1;q++) mc = fmaxf(mc, c[q]);
    float se = 0.f;
    #pragma unroll
    for (int q=0;q<NC1;q++) se += expf(c[q]-mc);
    float lseC = logf(se) + mc;
    float P0 = bc.x + lseC;
    float m2 = fmaxf(P0, mc + bc.y);
    float s2 = expf(P0 - m2);
    #pragma unroll
    for (int q=0;q<NC1;q++) s2 += expf(c[q] + bc.y - m2);
    float lseM = logf(s2) + m2;
    // select c[conf_t-1] with STATIC indices only (avoid scratch demotion)
    int sel = conf_t - 1;
    float csel = c[0];
    #pragma unroll
    for (int q=1;q<NC1;q++) csel = (sel == q) ? c[q] : csel;
    float g = (conf_t==0) ? P0 : (csel + bc.y);
    ceM = lseM - g;
    ceBinOut[idx] = isPos ? 0.f : ceB;
    ceMulOut[idx] = isPos ? 0.f : ceM;
    posOut[idx] = isPos ? 1.f : 0.f;
  }
  float a0 = isPos ? sl1 : 0.f;
  float a1 = isPos ? ceM : 0.f;
  float a2 = isPos ? ceB : 0.f;
  int cnt = isPos;
  #pragma unroll
  for (int off=32; off>0; off>>=1){
    a0 += __shfl_down(a0, off);
    a1 += __shfl_down(a1, off);
    a2 += __shfl_down(a2, off);
    cnt += __shfl_down(cnt, off);
  }
  if ((threadIdx.x & 63) == 0){
    if (cnt)        atomicAdd(&numPos[b], cnt);
    if (a0 != 0.f)  atomicAdd(&acc[0], (double)a0);
    if (a1 != 0.f)  atomicAdd(&acc[1], (double)a1);
    if (a2 != 0.f)  atomicAdd(&acc[2], (double)a2);
  }
}

// ---------------- exact top-k selection per row (stable-argsort semantics) ----------------
// 1024 threads/block (16 waves) for latency hiding; parallel suffix-scan bin selection.
__global__ __launch_bounds__(1024) void k_rank(const float* __restrict__ ceBin,
    const float* __restrict__ ceMul, const int* __restrict__ numPos,
    float* __restrict__ negBinOut, float* __restrict__ negMulOut, double* acc){
  const int b = blockIdx.x;
  const int which = blockIdx.y;        // 0 = binary loss, 1 = multiclass loss
  const float* arr = (which==0 ? ceBin : ceMul) + (size_t)b*NP;
  float* out = (which==0 ? negBinOut : negMulOut) + (size_t)b*NP;
  const int tid = threadIdx.x;
  int np = numPos[b];
  int k = min(3*np, NP-1);
  if (k <= 0){
    for (int i=tid; i<NP; i+=1024) out[i] = 0.f;
    return;
  }
  __shared__ u32 hist[256];
  __shared__ u32 scan[256];
  __shared__ u32 s_pref;
  __shared__ int s_rem;
  if (tid==0){ s_pref = 0u; s_rem = k; }
  if (tid < 256) hist[tid] = 0u;
  __syncthreads();
  for (int r=0; r<4; r++){
    u32 pref = s_pref;
    int sh = 24 - 8*r;
    for (int i=tid; i<NP; i+=1024){
      u32 s = f2s(arr[i]);
      if (r==0 || (s >> (sh+8)) == (pref >> (sh+8)))
        atomicAdd(&hist[(s >> sh) & 255u], 1u);
    }
    __syncthreads();
    // suffix-sum from the top: scan[bin] = # elements with digit >= bin (within prefix group)
    if (tid < 256) scan[tid] = hist[tid];
    __syncthreads();
    for (int st=1; st<256; st<<=1){
      u32 add = 0u;
      if (tid < 256 && tid + st < 256) add = scan[tid + st];
      __syncthreads();
      if (tid < 256) scan[tid] += add;
      __syncthreads();
    }
    if (tid < 256){
      u32 rem = (u32)s_rem;
      u32 inclusive = scan[tid];
      u32 above = (tid < 255) ? scan[tid+1] : 0u;
      if (inclusive >= rem && above < rem){   // exactly one bin satisfies this
        s_pref = pref | ((u32)tid << sh);
        s_rem  = (int)(rem - above);
      }
      hist[tid] = 0u;   // reset for next pass
    }
    __syncthreads();
  }
  const u32 kth = s_pref;     // exact k-th largest key
  const int need = s_rem;     // how many of the ties (by smallest index) are selected
  __shared__ int eqCnt;
  __shared__ int eqIdx[2048];
  if (tid==0) eqCnt = 0;
  __syncthreads();
  float sum = 0.f;
  for (int i=tid; i<NP; i+=1024){
    float v = arr[i];
    u32 s = f2s(v);
    float o = 0.f;
    if (s > kth){ o = 1.f; sum += v; }
    else if (s == kth){ int p = atomicAdd(&eqCnt, 1); if (p < 2048) eqIdx[p] = i; }
    out[i] = o;
  }
  __syncthreads();
  int ec = min(eqCnt, 2048);
  for (int e=tid; e<ec; e+=1024){
    int idx = eqIdx[e]; int rank = 0;
    for (int f=0; f<ec; f++) rank += (eqIdx[f] < idx) ? 1 : 0;
    if (rank < need){ out[idx] = 1.f; sum += arr[idx]; }
  }
  if (which==0){
    #pragma unroll
    for (int off=32; off>0; off>>=1) sum += __shfl_down(sum, off);
    if ((tid & 63) == 0 && sum != 0.f) atomicAdd(&acc[3], (double)sum);
  }
}

// ---------------- finalize scalars ----------------
__global__ void k_final(const int* numPos, const double* acc, float* out){
  if (threadIdx.x==0 && blockIdx.x==0){
    int s = 0;
    for (int b=0; b<NB; b++) s += numPos[b];
    float N = fmaxf((float)s, 1.0f);
    out[0] = (float)(acc[0] / (double)N);                 // loss_l / N
    out[1] = (float)(acc[1] / (double)N);                 // loss_cls / N
    out[2] = (float)((acc[2] + 3.0*acc[3]) / (double)N);  // loss_b / N  (w_bin[0]=3 on negatives)
  }
}

extern "C" void kernel_launch(void* const* d_in, const int* in_sizes, int n_in,
                              void* d_out, int out_size, void* d_ws, size_t ws_size,
                              hipStream_t stream) {
  const float* loc     = (const float*)d_in[0];
  const float* conf    = (const float*)d_in[1];
  const float* binc    = (const float*)d_in[2];
  const float* priors  = (const float*)d_in[3];
  const float* targets = (const float*)d_in[4];
  float* out = (float*)d_out;

  char* ws = (char*)d_ws;
  float* ovArr  = (float*)ws;                                   // NB*NP f32 -> reused as ceBin
  int*   btIdx  = (int*)(ws + (size_t)NB*NP*4);                 // NB*NP i32 -> reused as ceMul
  int*   ovr    = (int*)(ws + (size_t)NB*NP*8);                 // NB*NP i32
  u64*   bpKey  = (u64*)(ws + (size_t)NB*NP*12);                // NB*NOBJ u64
  int*   numPos = (int*)(ws + (size_t)NB*NP*12 + NB*NOBJ*8);    // NB i32
  double* acc   = (double*)(ws + (size_t)NB*NP*12 + NB*NOBJ*8 + NB*4); // 4 f64

  float* posOut    = out + 3;
  float* negBinOut = out + 3 + (size_t)NB*NP;
  float* negMulOut = out + 3 + (size_t)2*NB*NP;

  const int pbBlocks = (NP + 255)/256;      // 96
  k_init<<<(NB*NP + 255)/256, 256, 0, stream>>>(ovr, bpKey, numPos, acc);
  k_match<<<dim3(pbBlocks, NB), 256, 0, stream>>>(priors, targets, ovArr, btIdx, bpKey);
  k_scatter<<<(NB*NOBJ + 255)/256, 256, 0, stream>>>(bpKey, ovArr, ovr);
  k_loss<<<dim3(pbBlocks, NB), 256, 0, stream>>>(loc, conf, binc, priors, targets,
      ovArr, btIdx, ovr, ovArr /*ceBin*/, (float*)btIdx /*ceMul*/, posOut, numPos, acc);
  k_rank<<<dim3(NB, 2), 1024, 0, stream>>>(ovArr, (const float*)btIdx, numPos,
      negBinOut, negMulOut, acc);
  k_final<<<1, 64, 0, stream>>>(numPos, acc, out);
}